// Round 1
// baseline (195.443 us; speedup 1.0000x reference)
//
#include <hip/hip_runtime.h>
#include <cstdint>

typedef unsigned short ushort_t;
typedef short short8 __attribute__((ext_vector_type(8)));
typedef float f32x4 __attribute__((ext_vector_type(4)));
typedef float float4v __attribute__((ext_vector_type(4)));
typedef unsigned int uint2v __attribute__((ext_vector_type(2)));

#define DDIM 1024
#define HH 16
#define HEADK 64
#define BB 2
#define SS 2048

#if __has_builtin(__builtin_amdgcn_exp2f)
#define EXP2F(x) __builtin_amdgcn_exp2f(x)
#else
#define EXP2F(x) exp2f(x)
#endif

__device__ __forceinline__ ushort_t f2bf(float f) {
  union { float f; uint32_t u; } c; c.f = f;
  uint32_t u = c.u;
  u += 0x7fffu + ((u >> 16) & 1u);
  return (ushort_t)(u >> 16);
}

// truncation-pack two fp32 -> bf16x2 (1 v_perm). Bias cancels in l-normalization.
__device__ __forceinline__ uint32_t pkbf_trunc(float a, float b) {
  union { float f; uint32_t u; } ca, cb;
  ca.f = a; cb.f = b;
  return __builtin_amdgcn_perm(cb.u, ca.u, 0x07060302);
}

__device__ __forceinline__ uint32_t pkbf_rne(float a, float b) {
  return (uint32_t)f2bf(a) | ((uint32_t)f2bf(b) << 16);
}

__device__ __forceinline__ float bfhi2f(uint32_t u) {  // high half
  union { uint32_t u; float f; } c; c.u = u & 0xffff0000u; return c.f;
}
__device__ __forceinline__ float bflo2f(uint32_t u) {  // low half
  union { uint32_t u; float f; } c; c.u = u << 16; return c.f;
}

__device__ __forceinline__ void glds16(const ushort_t* gp, ushort_t* lp) {
  __builtin_amdgcn_global_load_lds(
      (const __attribute__((address_space(1))) uint32_t*)gp,
      (__attribute__((address_space(3))) uint32_t*)lp, 16, 0, 0);
}

// ---------------- fp32 -> bf16 convert, 3 tensors in one launch ----------------
__global__ void cvt3_kernel(const float* __restrict__ s0, ushort_t* __restrict__ d0, int n0,
                            const float* __restrict__ s1, ushort_t* __restrict__ d1, int n1,
                            const float* __restrict__ s2, ushort_t* __restrict__ d2, int n2) {
  int i = blockIdx.x * blockDim.x + threadIdx.x;
  const float* src; ushort_t* dst; int k;
  if (i < n0) { src = s0; dst = d0; k = i; }
  else if (i < n0 + n1) { src = s1; dst = d1; k = i - n0; }
  else if (i < n0 + n1 + n2) { src = s2; dst = d2; k = i - n0 - n1; }
  else return;
  float4v v = ((const float4v*)src)[k];
  uint2v o; o[0] = pkbf_rne(v[0], v[1]); o[1] = pkbf_rne(v[2], v[3]);
  ((uint2v*)dst)[k] = o;
}

// ---------------- NT GEMM: C[M,N] = A[M,Kd] * Bm[N,Kd]^T + bias ----------------
// (unchanged from round 11)
template <int MODE, int TM>
__global__ __launch_bounds__(256) void gemm_nt(
    const ushort_t* __restrict__ A, const ushort_t* __restrict__ Bm,
    const float* __restrict__ bias, float* __restrict__ Cout,
    ushort_t* __restrict__ Cbf, int M, int N, int Kd) {
  __shared__ ushort_t smem[128 * 64 * 2];
  ushort_t* As = smem;
  ushort_t* Bs = smem + TM * 64;
  const int MI = TM / 32;
  const int tid = threadIdx.x;
  const int wv = tid >> 6, lane = tid & 63;
  const int l15 = lane & 15, quad = lane >> 4;
  const int wm = wv >> 1, wn = wv & 1;
  const int tm0 = blockIdx.y * TM, tn0 = blockIdx.x * 128;

  f32x4 acc[MI][4];
#pragma unroll
  for (int i = 0; i < MI; ++i)
#pragma unroll
    for (int j = 0; j < 4; ++j) acc[i][j] = (f32x4){0.f, 0.f, 0.f, 0.f};

  const int lrow = lane >> 3;
  const int gcb = (lane & 7) ^ lrow;
  const int ACI = TM / 32;

  for (int k0 = 0; k0 < Kd; k0 += 64) {
#pragma unroll
    for (int c = 0; c < ACI; ++c) {
      int seg = wv * ACI + c;
      glds16(A + (size_t)(tm0 + seg * 8 + lrow) * Kd + k0 + gcb * 8,
             As + seg * 512);
    }
#pragma unroll
    for (int c = 0; c < 4; ++c) {
      int seg = wv * 4 + c;
      glds16(Bm + (size_t)(tn0 + seg * 8 + lrow) * Kd + k0 + gcb * 8,
             Bs + seg * 512);
    }
    __syncthreads();
#pragma unroll
    for (int kk = 0; kk < 64; kk += 32) {
      short8 af[MI], bfr[4];
#pragma unroll
      for (int i = 0; i < MI; ++i) {
        int r = wm * (TM / 2) + i * 16 + l15;
        int cb = (kk >> 3) + quad;
        af[i] = *(const short8*)(As + r * 64 + ((cb ^ (l15 & 7)) << 3));
      }
#pragma unroll
      for (int j = 0; j < 4; ++j) {
        int r = wn * 64 + j * 16 + l15;
        int cb = (kk >> 3) + quad;
        bfr[j] = *(const short8*)(Bs + r * 64 + ((cb ^ (l15 & 7)) << 3));
      }
#pragma unroll
      for (int i = 0; i < MI; ++i)
#pragma unroll
        for (int j = 0; j < 4; ++j)
          acc[i][j] = __builtin_amdgcn_mfma_f32_16x16x32_bf16(
              af[i], bfr[j], acc[i][j], 0, 0, 0);
    }
    __syncthreads();
  }

  if (MODE == 1) {
#pragma unroll
    for (int j = 0; j < 4; ++j) {
      int col = tn0 + wn * 64 + j * 16 + l15;
      float bv = bias[col];
#pragma unroll
      for (int i = 0; i < MI; ++i) {
        int row0 = tm0 + wm * (TM / 2) + i * 16 + quad * 4;
#pragma unroll
        for (int r = 0; r < 4; ++r)
          Cout[(size_t)(row0 + r) * N + col] = acc[i][j][r] + bv;
      }
    }
  } else {
    const int t = tn0 >> 10;
    if (t < 2) {
#pragma unroll
      for (int j = 0; j < 4; ++j) {
        int col = tn0 + wn * 64 + j * 16 + l15;
        float bv = bias[col];
        int hh = (col >> 6) & 15, kk2 = col & 63;
#pragma unroll
        for (int i = 0; i < MI; ++i) {
          int row0 = tm0 + wm * (TM / 2) + i * 16 + quad * 4;
#pragma unroll
          for (int r = 0; r < 4; ++r) {
            int row = row0 + r;
            int b = row >> 11, s = row & 2047;
            float v = acc[i][j][r] + bv;
            if (t == 0) v *= 0.18033688f;  // 0.125*log2(e)
            size_t base =
                (((size_t)t * BB + b) * HH + hh) * ((size_t)SS * HEADK);
            Cbf[base + (size_t)s * HEADK + kk2] = f2bf(v);
          }
        }
      }
    } else {
      __syncthreads();
#pragma unroll
      for (int j = 0; j < 4; ++j) {
        int c = wn * 64 + j * 16 + l15;
        float bv = bias[tn0 + c];
#pragma unroll
        for (int i = 0; i < MI; ++i) {
          int row0 = wm * (TM / 2) + i * 16 + quad * 4;
          uint2v dw;
          dw[0] = pkbf_rne(acc[i][j][0] + bv, acc[i][j][1] + bv);
          dw[1] = pkbf_rne(acc[i][j][2] + bv, acc[i][j][3] + bv);
          int rb = row0 >> 3;
          *(uint2v*)(&smem[c * 128 + (((rb ^ (c & 15)) << 3) | (row0 & 7))]) =
              dw;
        }
      }
      __syncthreads();
      const int rb2 = lane & 15;
      const int cg = lane >> 4;
#pragma unroll
      for (int it = 0; it < 8; ++it) {
        int c = wv * 32 + it * 4 + cg;
        short8 vv = *(const short8*)(&smem[c * 128 + ((rb2 ^ (c & 15)) << 3)]);
        int gcol = tn0 + c;
        int hh = (gcol >> 6) & 15, kk2 = gcol & 63;
        int grow = tm0 + rb2 * 8;
        int b = grow >> 11, s = grow & 2047;
        size_t base = (((size_t)2 * BB + b) * HH + hh) * ((size_t)SS * HEADK);
        *(short8*)(&Cbf[base + (size_t)kk2 * SS + s]) = vv;
      }
    }
  }
}

// ---------------- flash attention, KV-split ----------------
// grid (16,16,B*NSPLIT): qt=bx (128 q-rows), h=by, z: b=z/NSPLIT, ns=z%NSPLIT.
// 4 waves x 32 q-rows; KV tile 32, TRIPLE-buffered, staged 2 tiles ahead with
// counted s_waitcnt vmcnt(2) + raw s_barrier (T3+T4): prefetch loads stay in
// flight across the barrier instead of the vmcnt(0) drain __syncthreads forces.
// LDS 32 KB -> 5 blocks/CU; NSPLIT=4 gives 2048 blocks -> 20 waves/CU.
// Max-free exp2 softmax => partials exactly additive for any NSPLIT: block
// writes unnormalized O^T (bf16, per-split buffer) + l (fp32); reduce combines.
template <int NSPLIT>
__global__ __launch_bounds__(256, 4) void attn_kernel(
    const ushort_t* __restrict__ qkv, ushort_t* __restrict__ O0,
    ushort_t* __restrict__ O1, ushort_t* __restrict__ O2,
    ushort_t* __restrict__ O3, float* __restrict__ Lp) {
  constexpr int NT = (SS / NSPLIT) / 32;  // KV tiles per block
  __shared__ ushort_t Kt[3][32 * 64];   // [pos32][feat64], XOR-swizzled
  __shared__ ushort_t Vt[3][64 * 32];   // [feat64][pos32], XOR-swizzled
  __shared__ ushort_t Pw[4][32 * 32];   // per-wave P; reused 16x64 in epilogue

  const int qt = blockIdx.x, h = blockIdx.y;
  const int b = blockIdx.z / NSPLIT, ns = blockIdx.z % NSPLIT;
  const int tid = threadIdx.x;
  const int wv = tid >> 6, lane = tid & 63;
  const int l15 = lane & 15, quad = lane >> 4;

  const size_t hstride = (size_t)SS * HEADK;
  const ushort_t* Qg = qkv + ((size_t)(0 * BB + b) * HH + h) * hstride;
  const ushort_t* Kg = qkv + ((size_t)(1 * BB + b) * HH + h) * hstride;
  const ushort_t* Vg = qkv + ((size_t)(2 * BB + b) * HH + h) * hstride; // [64][2048]
  ushort_t* Opp;
  if (NSPLIT == 2) {
    Opp = ns ? O1 : O0;
  } else {
    Opp = (ns == 0) ? O0 : (ns == 1) ? O1 : (ns == 2) ? O2 : O3;
  }

  short8 qf[2][2];
#pragma unroll
  for (int mi = 0; mi < 2; ++mi)
#pragma unroll
    for (int kc = 0; kc < 2; ++kc)
      qf[mi][kc] = *(const short8*)(
          Qg + (size_t)(qt * 128 + wv * 32 + mi * 16 + l15) * 64 + kc * 32 +
          quad * 8);

  const short ONE = (short)0x3F80;
  short8 ones = {ONE, ONE, ONE, ONE, ONE, ONE, ONE, ONE};

  f32x4 oat[2][4];  // O^T rows feat=cf*16+quad*4+r, col qrow=l15
  f32x4 loa[2];
#pragma unroll
  for (int mi = 0; mi < 2; ++mi) {
    loa[mi] = (f32x4){0.f, 0.f, 0.f, 0.f};
#pragma unroll
    for (int c = 0; c < 4; ++c) oat[mi][c] = (f32x4){0.f, 0.f, 0.f, 0.f};
  }

  const int lrow = lane >> 3, gcb = (lane & 7) ^ lrow;   // K staging
  const int vfl = lane >> 2;                              // V staging feat 0..15
  const int vgb = (lane & 3) ^ ((vfl >> 1) & 3);          // V global pos-block

  const int pos0 = ns * (SS / NSPLIT);

  // 2 glds16 per wave per tile -> per-wave vmcnt accounting below
  auto stage = [&](int jj, int db) {
    glds16(Kg + (size_t)(pos0 + jj * 32 + wv * 8 + lrow) * 64 + gcb * 8,
           &Kt[db][wv * 512]);
    glds16(Vg + (size_t)(wv * 16 + vfl) * SS + pos0 + jj * 32 + vgb * 8,
           &Vt[db][wv * 512]);
  };

  stage(0, 0);
  stage(1, 1);

  int cur = 0;
  for (int j = 0; j < NT; ++j) {
    // Tile j's loads (mine: all but the newest 2 outstanding) must be done;
    // tile j+1's 2 loads stay in flight across the barrier. Last iter drains.
    if (j + 1 < NT)
      asm volatile("s_waitcnt vmcnt(2)" ::: "memory");
    else
      asm volatile("s_waitcnt vmcnt(0)" ::: "memory");
    __builtin_amdgcn_s_barrier();
    asm volatile("" ::: "memory");          // IR-level fence: no LDS-read hoist
    __builtin_amdgcn_sched_barrier(0);      // MIR-level fence (rule 18)

    if (j + 2 < NT) {
      int tgt = cur + 2;
      if (tgt >= 3) tgt -= 3;  // buffer read in iter j-1; safe after barrier
      stage(j + 2, tgt);
    }

    // S^T frags: rows pos = cf*16+quad*4+r (cf 0..1), col qrow = l15
    f32x4 st[2][2];
    __builtin_amdgcn_s_setprio(1);
#pragma unroll
    for (int cf = 0; cf < 2; ++cf) {
      int n = cf * 16 + l15;
      short8 kf0 = *(const short8*)(&Kt[cur][n * 64 + ((quad ^ (n & 7)) << 3)]);
      short8 kf1 =
          *(const short8*)(&Kt[cur][n * 64 + (((quad + 4) ^ (n & 7)) << 3)]);
#pragma unroll
      for (int mi = 0; mi < 2; ++mi) {
        f32x4 z = (f32x4){0.f, 0.f, 0.f, 0.f};
        z = __builtin_amdgcn_mfma_f32_16x16x32_bf16(kf0, qf[mi][0], z, 0, 0, 0);
        z = __builtin_amdgcn_mfma_f32_16x16x32_bf16(kf1, qf[mi][1], z, 0, 0, 0);
        st[mi][cf] = z;
      }
    }
    __builtin_amdgcn_s_setprio(0);

    // P = exp2(S^T) -> per-wave LDS [qrow32][pos32], swizzle (qrow>>1)&3
#pragma unroll
    for (int mi = 0; mi < 2; ++mi)
#pragma unroll
      for (int cf = 0; cf < 2; ++cf) {
        float e0 = EXP2F(st[mi][cf][0]);
        float e1 = EXP2F(st[mi][cf][1]);
        float e2 = EXP2F(st[mi][cf][2]);
        float e3 = EXP2F(st[mi][cf][3]);
        uint2v dw;
        dw[0] = pkbf_trunc(e0, e1);
        dw[1] = pkbf_trunc(e2, e3);
        int row = mi * 16 + l15;
        int pb = 2 * cf + (quad >> 1);
        int pbs = pb ^ ((l15 >> 1) & 3);
        *(uint2v*)(&Pw[wv][row * 32 + pbs * 8 + (quad & 1) * 4]) = dw;
      }

    // P as B-operand frags (row qrow=l15, k=pos 0..31)
    short8 pa[2];
#pragma unroll
    for (int mi = 0; mi < 2; ++mi) {
      int row = mi * 16 + l15;
      pa[mi] = *(const short8*)(&Pw[wv][row * 32 +
                                        ((quad ^ ((l15 >> 1) & 3)) << 3)]);
    }

    // O^T += V^T * P ; l += ones * P
    __builtin_amdgcn_s_setprio(1);
#pragma unroll
    for (int cf = 0; cf < 4; ++cf) {
      short8 vf = *(const short8*)(&Vt[cur][(cf * 16 + l15) * 32 +
                                            ((quad ^ ((l15 >> 1) & 3)) << 3)]);
#pragma unroll
      for (int mi = 0; mi < 2; ++mi)
        oat[mi][cf] = __builtin_amdgcn_mfma_f32_16x16x32_bf16(
            vf, pa[mi], oat[mi][cf], 0, 0, 0);
    }
#pragma unroll
    for (int mi = 0; mi < 2; ++mi)
      loa[mi] = __builtin_amdgcn_mfma_f32_16x16x32_bf16(ones, pa[mi], loa[mi],
                                                        0, 0, 0);
    __builtin_amdgcn_s_setprio(0);

    cur = (cur == 2) ? 0 : cur + 1;
  }

  // epilogue: unnormalized O^T -> [qrow][feat] via per-wave Pw slab (16x64)
  const size_t obase = ((size_t)b * HH + h) * SS * HEADK;  // Opp[b][h][qrow][64]
#pragma unroll
  for (int mi = 0; mi < 2; ++mi) {
#pragma unroll
    for (int cf = 0; cf < 4; ++cf) {
      uint2v dw;
      dw[0] = pkbf_rne(oat[mi][cf][0], oat[mi][cf][1]);
      dw[1] = pkbf_rne(oat[mi][cf][2], oat[mi][cf][3]);
      int cb = 2 * cf + (quad >> 1);
      int cbs = cb ^ (l15 & 7);
      *(uint2v*)(&Pw[wv][l15 * 64 + cbs * 8 + (quad & 1) * 4]) = dw;
    }
    // same-wave DS ops are ordered: reads below see the writes above
    const int r = lane >> 2;
#pragma unroll
    for (int pass = 0; pass < 2; ++pass) {
      int g = (lane & 3) + 4 * pass;
      short8 ov = *(const short8*)(&Pw[wv][r * 64 + ((g ^ (r & 7)) << 3)]);
      int qrow = qt * 128 + wv * 32 + mi * 16 + r;
      *(short8*)(&Opp[obase + (size_t)qrow * 64 + g * 8]) = ov;
    }
    if (quad == 0) {
      int qrow = qt * 128 + wv * 32 + mi * 16 + l15;
      Lp[((size_t)(ns * BB + b) * HH + h) * SS + qrow] = loa[mi][0];
    }
  }
}

// ---------------- combine the NSPLIT KV-split partials ----------------
template <int NSPLIT>
__global__ void reduce_kernel(const ushort_t* __restrict__ O0,
                              const ushort_t* __restrict__ O1,
                              const ushort_t* __restrict__ O2,
                              const ushort_t* __restrict__ O3,
                              const float* __restrict__ Lp,
                              ushort_t* __restrict__ ob) {
  const size_t nsL = (size_t)BB * HH * SS;
  int c = blockIdx.x * blockDim.x + threadIdx.x;     // 8-elem chunk id
  int fc = c & 7;
  int hh = (c >> 3) & 15;
  int row = c >> 7;                                  // b*2048 + s
  int b = row >> 11, s = row & 2047;
  size_t po = (((size_t)b * HH + hh) * SS + s) * 64 + fc * 8;
  size_t lo = ((size_t)b * HH + hh) * SS + s;
  const ushort_t* Ops[4] = {O0, O1, O2, O3};
  float acc[8];
#pragma unroll
  for (int i = 0; i < 8; ++i) acc[i] = 0.f;
  float l = 0.f;
#pragma unroll
  for (int t = 0; t < NSPLIT; ++t) {
    uint2v a0 = *(const uint2v*)(&Ops[t][po]);
    uint2v a1 = *(const uint2v*)(&Ops[t][po + 4]);
    acc[0] += bflo2f(a0[0]); acc[1] += bfhi2f(a0[0]);
    acc[2] += bflo2f(a0[1]); acc[3] += bfhi2f(a0[1]);
    acc[4] += bflo2f(a1[0]); acc[5] += bfhi2f(a1[0]);
    acc[6] += bflo2f(a1[1]); acc[7] += bfhi2f(a1[1]);
    l += Lp[(size_t)t * nsL + lo];
  }
  float inv = 1.0f / l;
  uint2v o0, o1;
  o0[0] = pkbf_rne(acc[0] * inv, acc[1] * inv);
  o0[1] = pkbf_rne(acc[2] * inv, acc[3] * inv);
  o1[0] = pkbf_rne(acc[4] * inv, acc[5] * inv);
  o1[1] = pkbf_rne(acc[6] * inv, acc[7] * inv);
  size_t oo = ((size_t)(b * SS + s)) * DDIM + hh * 64 + fc * 8;
  *(uint2v*)(&ob[oo]) = o0;
  *(uint2v*)(&ob[oo + 4]) = o1;
}

extern "C" void kernel_launch(void* const* d_in, const int* in_sizes, int n_in,
                              void* d_out, int out_size, void* d_ws,
                              size_t ws_size, hipStream_t stream) {
  const float* x = (const float*)d_in[0];
  const float* Wqkv = (const float*)d_in[1];
  const float* bqkv = (const float*)d_in[2];
  const float* Wproj = (const float*)d_in[3];
  const float* bproj = (const float*)d_in[4];
  float* out = (float*)d_out;

  // Workspace plan (bytes):
  //   [0        .. 8388608)   xb   (GEMM1 A)  -> reused as Op0 by attn
  //   [8388608  .. 14680064)  wqb  (GEMM1 B)  -> reused as Lp by attn
  //   [14680064 .. 16777216)  wpb  (GEMM2 B, alive throughout)
  //   [16777216 .. 41943040)  qkvb (attn in)  -> reused as obuf by reduce
  //   [41943040 .. 50331648)  Op1
  //   [50331648 .. 58720256)  Op2  (4-way split only)
  //   [58720256 .. 67108864)  Op3  (4-way split only)
  // 2-way peak 48 MiB (proven layout); 4-way peak exactly 64 MiB.
  ushort_t* xb = (ushort_t*)d_ws;
  ushort_t* wqb = xb + (size_t)4096 * 1024;
  ushort_t* wpb = wqb + (size_t)3072 * 1024;
  ushort_t* qkvb = wpb + (size_t)1024 * 1024;
  ushort_t* Op1 = qkvb + (size_t)3 * BB * HH * SS * HEADK;
  ushort_t* Op2 = Op1 + (size_t)BB * HH * SS * HEADK;
  ushort_t* Op3 = Op2 + (size_t)BB * HH * SS * HEADK;
  ushort_t* Op0 = xb;
  float* Lp = (float*)wqb;
  ushort_t* obuf = qkvb;

  const int n0 = 4096 * 1024 / 4, n1 = 3072 * 1024 / 4, n2 = 1024 * 1024 / 4;
  cvt3_kernel<<<(n0 + n1 + n2 + 255) / 256, 256, 0, stream>>>(
      x, xb, n0, Wqkv, wqb, n1, Wproj, wpb, n2);
  gemm_nt<0, 128><<<dim3(3072 / 128, 4096 / 128), 256, 0, stream>>>(
      xb, wqb, bqkv, nullptr, qkvb, 4096, 3072, 1024);

  const size_t need4 = 67108864ull;  // 64 MiB for 4-way partials
  if (ws_size >= need4) {
    attn_kernel<4><<<dim3(16, 16, BB * 4), 256, 0, stream>>>(qkvb, Op0, Op1,
                                                             Op2, Op3, Lp);
    reduce_kernel<4><<<(BB * SS * DDIM / 8) / 256, 256, 0, stream>>>(
        Op0, Op1, Op2, Op3, Lp, obuf);
  } else {
    attn_kernel<2><<<dim3(16, 16, BB * 2), 256, 0, stream>>>(qkvb, Op0, Op1,
                                                             Op1, Op1, Lp);
    reduce_kernel<2><<<(BB * SS * DDIM / 8) / 256, 256, 0, stream>>>(
        Op0, Op1, Op1, Op1, Lp, obuf);
  }
  gemm_nt<1, 64><<<dim3(1024 / 128, 4096 / 64), 256, 0, stream>>>(
      obuf, wpb, bproj, out, nullptr, 4096, 1024, 1024);
}

// Round 2
// 193.418 us; speedup vs baseline: 1.0105x; 1.0105x over previous
//
#include <hip/hip_runtime.h>
#include <cstdint>

typedef unsigned short ushort_t;
typedef short short8 __attribute__((ext_vector_type(8)));
typedef float f32x4 __attribute__((ext_vector_type(4)));
typedef float float4v __attribute__((ext_vector_type(4)));
typedef unsigned int uint2v __attribute__((ext_vector_type(2)));

#define DDIM 1024
#define HH 16
#define HEADK 64
#define BB 2
#define SS 2048

#if __has_builtin(__builtin_amdgcn_exp2f)
#define EXP2F(x) __builtin_amdgcn_exp2f(x)
#else
#define EXP2F(x) exp2f(x)
#endif

__device__ __forceinline__ ushort_t f2bf(float f) {
  union { float f; uint32_t u; } c; c.f = f;
  uint32_t u = c.u;
  u += 0x7fffu + ((u >> 16) & 1u);
  return (ushort_t)(u >> 16);
}

// truncation-pack two fp32 -> bf16x2 (1 v_perm). Bias cancels in l-normalization.
__device__ __forceinline__ uint32_t pkbf_trunc(float a, float b) {
  union { float f; uint32_t u; } ca, cb;
  ca.f = a; cb.f = b;
  return __builtin_amdgcn_perm(cb.u, ca.u, 0x07060302);
}

__device__ __forceinline__ uint32_t pkbf_rne(float a, float b) {
  return (uint32_t)f2bf(a) | ((uint32_t)f2bf(b) << 16);
}

__device__ __forceinline__ float bfhi2f(uint32_t u) {  // high half
  union { uint32_t u; float f; } c; c.u = u & 0xffff0000u; return c.f;
}
__device__ __forceinline__ float bflo2f(uint32_t u) {  // low half
  union { uint32_t u; float f; } c; c.u = u << 16; return c.f;
}

__device__ __forceinline__ void glds16(const ushort_t* gp, ushort_t* lp) {
  __builtin_amdgcn_global_load_lds(
      (const __attribute__((address_space(1))) uint32_t*)gp,
      (__attribute__((address_space(3))) uint32_t*)lp, 16, 0, 0);
}

// ---------------- fp32 -> bf16 convert, 3 tensors in one launch ----------------
__global__ void cvt3_kernel(const float* __restrict__ s0, ushort_t* __restrict__ d0, int n0,
                            const float* __restrict__ s1, ushort_t* __restrict__ d1, int n1,
                            const float* __restrict__ s2, ushort_t* __restrict__ d2, int n2) {
  int i = blockIdx.x * blockDim.x + threadIdx.x;
  const float* src; ushort_t* dst; int k;
  if (i < n0) { src = s0; dst = d0; k = i; }
  else if (i < n0 + n1) { src = s1; dst = d1; k = i - n0; }
  else if (i < n0 + n1 + n2) { src = s2; dst = d2; k = i - n0 - n1; }
  else return;
  float4v v = ((const float4v*)src)[k];
  uint2v o; o[0] = pkbf_rne(v[0], v[1]); o[1] = pkbf_rne(v[2], v[3]);
  ((uint2v*)dst)[k] = o;
}

// ---------------- NT GEMM: C[M,N] = A[M,Kd] * Bm[N,Kd]^T + bias ----------------
// (unchanged from round 11)
template <int MODE, int TM>
__global__ __launch_bounds__(256) void gemm_nt(
    const ushort_t* __restrict__ A, const ushort_t* __restrict__ Bm,
    const float* __restrict__ bias, float* __restrict__ Cout,
    ushort_t* __restrict__ Cbf, int M, int N, int Kd) {
  __shared__ ushort_t smem[128 * 64 * 2];
  ushort_t* As = smem;
  ushort_t* Bs = smem + TM * 64;
  const int MI = TM / 32;
  const int tid = threadIdx.x;
  const int wv = tid >> 6, lane = tid & 63;
  const int l15 = lane & 15, quad = lane >> 4;
  const int wm = wv >> 1, wn = wv & 1;
  const int tm0 = blockIdx.y * TM, tn0 = blockIdx.x * 128;

  f32x4 acc[MI][4];
#pragma unroll
  for (int i = 0; i < MI; ++i)
#pragma unroll
    for (int j = 0; j < 4; ++j) acc[i][j] = (f32x4){0.f, 0.f, 0.f, 0.f};

  const int lrow = lane >> 3;
  const int gcb = (lane & 7) ^ lrow;
  const int ACI = TM / 32;

  for (int k0 = 0; k0 < Kd; k0 += 64) {
#pragma unroll
    for (int c = 0; c < ACI; ++c) {
      int seg = wv * ACI + c;
      glds16(A + (size_t)(tm0 + seg * 8 + lrow) * Kd + k0 + gcb * 8,
             As + seg * 512);
    }
#pragma unroll
    for (int c = 0; c < 4; ++c) {
      int seg = wv * 4 + c;
      glds16(Bm + (size_t)(tn0 + seg * 8 + lrow) * Kd + k0 + gcb * 8,
             Bs + seg * 512);
    }
    __syncthreads();
#pragma unroll
    for (int kk = 0; kk < 64; kk += 32) {
      short8 af[MI], bfr[4];
#pragma unroll
      for (int i = 0; i < MI; ++i) {
        int r = wm * (TM / 2) + i * 16 + l15;
        int cb = (kk >> 3) + quad;
        af[i] = *(const short8*)(As + r * 64 + ((cb ^ (l15 & 7)) << 3));
      }
#pragma unroll
      for (int j = 0; j < 4; ++j) {
        int r = wn * 64 + j * 16 + l15;
        int cb = (kk >> 3) + quad;
        bfr[j] = *(const short8*)(Bs + r * 64 + ((cb ^ (l15 & 7)) << 3));
      }
#pragma unroll
      for (int i = 0; i < MI; ++i)
#pragma unroll
        for (int j = 0; j < 4; ++j)
          acc[i][j] = __builtin_amdgcn_mfma_f32_16x16x32_bf16(
              af[i], bfr[j], acc[i][j], 0, 0, 0);
    }
    __syncthreads();
  }

  if (MODE == 1) {
#pragma unroll
    for (int j = 0; j < 4; ++j) {
      int col = tn0 + wn * 64 + j * 16 + l15;
      float bv = bias[col];
#pragma unroll
      for (int i = 0; i < MI; ++i) {
        int row0 = tm0 + wm * (TM / 2) + i * 16 + quad * 4;
#pragma unroll
        for (int r = 0; r < 4; ++r)
          Cout[(size_t)(row0 + r) * N + col] = acc[i][j][r] + bv;
      }
    }
  } else {
    const int t = tn0 >> 10;
    if (t < 2) {
#pragma unroll
      for (int j = 0; j < 4; ++j) {
        int col = tn0 + wn * 64 + j * 16 + l15;
        float bv = bias[col];
        int hh = (col >> 6) & 15, kk2 = col & 63;
#pragma unroll
        for (int i = 0; i < MI; ++i) {
          int row0 = tm0 + wm * (TM / 2) + i * 16 + quad * 4;
#pragma unroll
          for (int r = 0; r < 4; ++r) {
            int row = row0 + r;
            int b = row >> 11, s = row & 2047;
            float v = acc[i][j][r] + bv;
            if (t == 0) v *= 0.18033688f;  // 0.125*log2(e)
            size_t base =
                (((size_t)t * BB + b) * HH + hh) * ((size_t)SS * HEADK);
            Cbf[base + (size_t)s * HEADK + kk2] = f2bf(v);
          }
        }
      }
    } else {
      __syncthreads();
#pragma unroll
      for (int j = 0; j < 4; ++j) {
        int c = wn * 64 + j * 16 + l15;
        float bv = bias[tn0 + c];
#pragma unroll
        for (int i = 0; i < MI; ++i) {
          int row0 = wm * (TM / 2) + i * 16 + quad * 4;
          uint2v dw;
          dw[0] = pkbf_rne(acc[i][j][0] + bv, acc[i][j][1] + bv);
          dw[1] = pkbf_rne(acc[i][j][2] + bv, acc[i][j][3] + bv);
          int rb = row0 >> 3;
          *(uint2v*)(&smem[c * 128 + (((rb ^ (c & 15)) << 3) | (row0 & 7))]) =
              dw;
        }
      }
      __syncthreads();
      const int rb2 = lane & 15;
      const int cg = lane >> 4;
#pragma unroll
      for (int it = 0; it < 8; ++it) {
        int c = wv * 32 + it * 4 + cg;
        short8 vv = *(const short8*)(&smem[c * 128 + ((rb2 ^ (c & 15)) << 3)]);
        int gcol = tn0 + c;
        int hh = (gcol >> 6) & 15, kk2 = gcol & 63;
        int grow = tm0 + rb2 * 8;
        int b = grow >> 11, s = grow & 2047;
        size_t base = (((size_t)2 * BB + b) * HH + hh) * ((size_t)SS * HEADK);
        *(short8*)(&Cbf[base + (size_t)kk2 * SS + s]) = vv;
      }
    }
  }
}

// ---------------- flash attention, KV-split, software-pipelined ----------------
// grid (16,16,BB*NSPLIT): qt=bx (128 q-rows), h=by, z: b=z/NSPLIT, ns=z%NSPLIT.
// 4 waves x 32 q-rows; KV tile 32, triple-buffered K/V, staged 2 tiles ahead.
// T15-style pipeline: iteration j computes QK^T(j+1) -> exp2 -> P write into
// ping-pong Pw[(j+1)&1], then PV(j) consuming P written ONE ITERATION AGO.
// This takes the ~120cyc LDS write->read P round-trip off the critical path
// and decouples the QK/VALU chain from the PV/MFMA chain inside an iteration.
// Max-free exp2 softmax => partials exactly additive: block writes
// unnormalized O^T (bf16, per-split buffer) + l (fp32); reduce combines.
template <int NSPLIT>
__global__ __launch_bounds__(256, 4) void attn_kernel(
    const ushort_t* __restrict__ qkv, ushort_t* __restrict__ O0,
    ushort_t* __restrict__ O1, float* __restrict__ Lp) {
  constexpr int NT = (SS / NSPLIT) / 32;  // KV tiles per block
  __shared__ ushort_t Kt[3][32 * 64];     // [pos32][feat64], XOR-swizzled
  __shared__ ushort_t Vt[3][64 * 32];     // [feat64][pos32], XOR-swizzled
  __shared__ ushort_t Pw[4][2][32 * 32];  // per-wave P, ping-pong; epilogue slab

  const int qt = blockIdx.x, h = blockIdx.y;
  const int b = blockIdx.z / NSPLIT, ns = blockIdx.z % NSPLIT;
  const int tid = threadIdx.x;
  const int wv = tid >> 6, lane = tid & 63;
  const int l15 = lane & 15, quad = lane >> 4;

  const size_t hstride = (size_t)SS * HEADK;
  const ushort_t* Qg = qkv + ((size_t)(0 * BB + b) * HH + h) * hstride;
  const ushort_t* Kg = qkv + ((size_t)(1 * BB + b) * HH + h) * hstride;
  const ushort_t* Vg = qkv + ((size_t)(2 * BB + b) * HH + h) * hstride; // [64][2048]
  ushort_t* Opp = ns ? O1 : O0;

  short8 qf[2][2];
#pragma unroll
  for (int mi = 0; mi < 2; ++mi)
#pragma unroll
    for (int kc = 0; kc < 2; ++kc)
      qf[mi][kc] = *(const short8*)(
          Qg + (size_t)(qt * 128 + wv * 32 + mi * 16 + l15) * 64 + kc * 32 +
          quad * 8);

  const short ONE = (short)0x3F80;
  short8 ones = {ONE, ONE, ONE, ONE, ONE, ONE, ONE, ONE};

  f32x4 oat[2][4];  // O^T rows feat=cf*16+quad*4+r, col qrow=l15
  f32x4 loa[2];
#pragma unroll
  for (int mi = 0; mi < 2; ++mi) {
    loa[mi] = (f32x4){0.f, 0.f, 0.f, 0.f};
#pragma unroll
    for (int c = 0; c < 4; ++c) oat[mi][c] = (f32x4){0.f, 0.f, 0.f, 0.f};
  }

  const int lrow = lane >> 3, gcb = (lane & 7) ^ lrow;   // K staging
  const int vfl = lane >> 2;                              // V staging feat 0..15
  const int vgb = (lane & 3) ^ ((vfl >> 1) & 3);          // V global pos-block

  const int pos0 = ns * (SS / NSPLIT);

  // 2 glds16 per wave per tile
  auto stage = [&](int jj, int db) {
    glds16(Kg + (size_t)(pos0 + jj * 32 + wv * 8 + lrow) * 64 + gcb * 8,
           &Kt[db][wv * 512]);
    glds16(Vg + (size_t)(wv * 16 + vfl) * SS + pos0 + jj * 32 + vgb * 8,
           &Vt[db][wv * 512]);
  };

  // QK^T(tile in Kt[kb]) -> exp2 -> P into Pw[wv][pb]
  auto qk_phase = [&](int kb, int pb) {
    f32x4 st[2][2];
    __builtin_amdgcn_s_setprio(1);
#pragma unroll
    for (int cf = 0; cf < 2; ++cf) {
      int n = cf * 16 + l15;
      short8 kf0 = *(const short8*)(&Kt[kb][n * 64 + ((quad ^ (n & 7)) << 3)]);
      short8 kf1 =
          *(const short8*)(&Kt[kb][n * 64 + (((quad + 4) ^ (n & 7)) << 3)]);
#pragma unroll
      for (int mi = 0; mi < 2; ++mi) {
        f32x4 z = (f32x4){0.f, 0.f, 0.f, 0.f};
        z = __builtin_amdgcn_mfma_f32_16x16x32_bf16(kf0, qf[mi][0], z, 0, 0, 0);
        z = __builtin_amdgcn_mfma_f32_16x16x32_bf16(kf1, qf[mi][1], z, 0, 0, 0);
        st[mi][cf] = z;
      }
    }
    __builtin_amdgcn_s_setprio(0);
#pragma unroll
    for (int mi = 0; mi < 2; ++mi)
#pragma unroll
      for (int cf = 0; cf < 2; ++cf) {
        float e0 = EXP2F(st[mi][cf][0]);
        float e1 = EXP2F(st[mi][cf][1]);
        float e2 = EXP2F(st[mi][cf][2]);
        float e3 = EXP2F(st[mi][cf][3]);
        uint2v dw;
        dw[0] = pkbf_trunc(e0, e1);
        dw[1] = pkbf_trunc(e2, e3);
        int row = mi * 16 + l15;
        int pbv = 2 * cf + (quad >> 1);
        int pbs = pbv ^ ((l15 >> 1) & 3);
        *(uint2v*)(&Pw[wv][pb][row * 32 + pbs * 8 + (quad & 1) * 4]) = dw;
      }
  };

  stage(0, 0);
  stage(1, 1);

  // prologue: tile 0's K landed everywhere -> QK(0), P(0) -> Pw[0]
  asm volatile("s_waitcnt vmcnt(2)" ::: "memory");
  __builtin_amdgcn_s_barrier();
  asm volatile("" ::: "memory");
  __builtin_amdgcn_sched_barrier(0);
  qk_phase(0, 0);

  int vb = 0;  // buffer holding tile j
  for (int j = 0; j < NT; ++j) {
    const int kb = (vb == 2) ? 0 : vb + 1;   // tile j+1
    const int sb = (kb == 2) ? 0 : kb + 1;   // tile j+2 (overwrites tile j-1)
    // stage(j+1) (issued at iter j-1) must be in LDS everywhere before QK(j+1);
    // barrier also guarantees all waves finished reading tile j-1 (buffer sb).
    asm volatile("s_waitcnt vmcnt(0)" ::: "memory");
    __builtin_amdgcn_s_barrier();
    asm volatile("" ::: "memory");
    __builtin_amdgcn_sched_barrier(0);

    if (j + 2 < NT) stage(j + 2, sb);
    if (j + 1 < NT) qk_phase(kb, (j + 1) & 1);

    // PV(j): consume P written one iteration ago (same-wave DS ordering)
    short8 pa[2];
#pragma unroll
    for (int mi = 0; mi < 2; ++mi) {
      int row = mi * 16 + l15;
      pa[mi] = *(const short8*)(&Pw[wv][j & 1][row * 32 +
                                              ((quad ^ ((l15 >> 1) & 3)) << 3)]);
    }
    __builtin_amdgcn_s_setprio(1);
#pragma unroll
    for (int cf = 0; cf < 4; ++cf) {
      short8 vf = *(const short8*)(&Vt[vb][(cf * 16 + l15) * 32 +
                                           ((quad ^ ((l15 >> 1) & 3)) << 3)]);
#pragma unroll
      for (int mi = 0; mi < 2; ++mi)
        oat[mi][cf] = __builtin_amdgcn_mfma_f32_16x16x32_bf16(
            vf, pa[mi], oat[mi][cf], 0, 0, 0);
    }
#pragma unroll
    for (int mi = 0; mi < 2; ++mi)
      loa[mi] = __builtin_amdgcn_mfma_f32_16x16x32_bf16(ones, pa[mi], loa[mi],
                                                        0, 0, 0);
    __builtin_amdgcn_s_setprio(0);

    vb = kb;
  }

  // epilogue: unnormalized O^T -> [qrow][feat] via per-wave Pw slab (16x64)
  const size_t obase = ((size_t)b * HH + h) * SS * HEADK;  // Opp[b][h][qrow][64]
#pragma unroll
  for (int mi = 0; mi < 2; ++mi) {
#pragma unroll
    for (int cf = 0; cf < 4; ++cf) {
      uint2v dw;
      dw[0] = pkbf_rne(oat[mi][cf][0], oat[mi][cf][1]);
      dw[1] = pkbf_rne(oat[mi][cf][2], oat[mi][cf][3]);
      int cb = 2 * cf + (quad >> 1);
      int cbs = cb ^ (l15 & 7);
      *(uint2v*)(&Pw[wv][0][l15 * 64 + cbs * 8 + (quad & 1) * 4]) = dw;
    }
    // same-wave DS ops are ordered: reads below see the writes above
    const int r = lane >> 2;
#pragma unroll
    for (int pass = 0; pass < 2; ++pass) {
      int g = (lane & 3) + 4 * pass;
      short8 ov = *(const short8*)(&Pw[wv][0][r * 64 + ((g ^ (r & 7)) << 3)]);
      int qrow = qt * 128 + wv * 32 + mi * 16 + r;
      *(short8*)(&Opp[obase + (size_t)qrow * 64 + g * 8]) = ov;
    }
    if (quad == 0) {
      int qrow = qt * 128 + wv * 32 + mi * 16 + l15;
      Lp[((size_t)(ns * BB + b) * HH + h) * SS + qrow] = loa[mi][0];
    }
  }
}

// ---------------- combine the NSPLIT KV-split partials ----------------
template <int NSPLIT>
__global__ void reduce_kernel(const ushort_t* __restrict__ O0,
                              const ushort_t* __restrict__ O1,
                              const float* __restrict__ Lp,
                              ushort_t* __restrict__ ob) {
  const size_t nsL = (size_t)BB * HH * SS;
  int c = blockIdx.x * blockDim.x + threadIdx.x;     // 8-elem chunk id
  int fc = c & 7;
  int hh = (c >> 3) & 15;
  int row = c >> 7;                                  // b*2048 + s
  int b = row >> 11, s = row & 2047;
  size_t po = (((size_t)b * HH + hh) * SS + s) * 64 + fc * 8;
  size_t lo = ((size_t)b * HH + hh) * SS + s;
  const ushort_t* Ops[2] = {O0, O1};
  float acc[8];
#pragma unroll
  for (int i = 0; i < 8; ++i) acc[i] = 0.f;
  float l = 0.f;
#pragma unroll
  for (int t = 0; t < NSPLIT; ++t) {
    uint2v a0 = *(const uint2v*)(&Ops[t][po]);
    uint2v a1 = *(const uint2v*)(&Ops[t][po + 4]);
    acc[0] += bflo2f(a0[0]); acc[1] += bfhi2f(a0[0]);
    acc[2] += bflo2f(a0[1]); acc[3] += bfhi2f(a0[1]);
    acc[4] += bflo2f(a1[0]); acc[5] += bfhi2f(a1[0]);
    acc[6] += bflo2f(a1[1]); acc[7] += bfhi2f(a1[1]);
    l += Lp[(size_t)t * nsL + lo];
  }
  float inv = 1.0f / l;
  uint2v o0, o1;
  o0[0] = pkbf_rne(acc[0] * inv, acc[1] * inv);
  o0[1] = pkbf_rne(acc[2] * inv, acc[3] * inv);
  o1[0] = pkbf_rne(acc[4] * inv, acc[5] * inv);
  o1[1] = pkbf_rne(acc[6] * inv, acc[7] * inv);
  size_t oo = ((size_t)(b * SS + s)) * DDIM + hh * 64 + fc * 8;
  *(uint2v*)(&ob[oo]) = o0;
  *(uint2v*)(&ob[oo + 4]) = o1;
}

extern "C" void kernel_launch(void* const* d_in, const int* in_sizes, int n_in,
                              void* d_out, int out_size, void* d_ws,
                              size_t ws_size, hipStream_t stream) {
  const float* x = (const float*)d_in[0];
  const float* Wqkv = (const float*)d_in[1];
  const float* bqkv = (const float*)d_in[2];
  const float* Wproj = (const float*)d_in[3];
  const float* bproj = (const float*)d_in[4];
  float* out = (float*)d_out;

  // Workspace plan (peak 50.33 MB, identical to proven rounds 1-11):
  //   [0      .. 4.19M)  xb   (GEMM1 A)      -> reused as Op0 by attn
  //   [4.19M  .. 7.34M)  wqb  (GEMM1 B)      -> reused as Lp by attn
  //   [7.34M  .. 8.39M)  wpb  (GEMM2 B, alive throughout)
  //   [8.39M  .. 20.97M) qkvb (attn input)   -> reused as obuf by reduce
  //   [20.97M .. 25.17M) Op1
  ushort_t* xb = (ushort_t*)d_ws;
  ushort_t* wqb = xb + (size_t)4096 * 1024;
  ushort_t* wpb = wqb + (size_t)3072 * 1024;
  ushort_t* qkvb = wpb + (size_t)1024 * 1024;
  ushort_t* Op1 = qkvb + (size_t)3 * BB * HH * SS * HEADK;
  ushort_t* Op0 = xb;
  float* Lp = (float*)wqb;
  ushort_t* obuf = qkvb;

  const int n0 = 4096 * 1024 / 4, n1 = 3072 * 1024 / 4, n2 = 1024 * 1024 / 4;
  cvt3_kernel<<<(n0 + n1 + n2 + 255) / 256, 256, 0, stream>>>(
      x, xb, n0, Wqkv, wqb, n1, Wproj, wpb, n2);
  gemm_nt<0, 128><<<dim3(3072 / 128, 4096 / 128), 256, 0, stream>>>(
      xb, wqb, bqkv, nullptr, qkvb, 4096, 3072, 1024);
  attn_kernel<2><<<dim3(16, 16, BB * 2), 256, 0, stream>>>(qkvb, Op0, Op1, Lp);
  reduce_kernel<2><<<(BB * SS * DDIM / 8) / 256, 256, 0, stream>>>(Op0, Op1,
                                                                   Lp, obuf);
  gemm_nt<1, 64><<<dim3(1024 / 128, 4096 / 64), 256, 0, stream>>>(
      obuf, wpb, bproj, out, nullptr, 4096, 1024, 1024);
}

// Round 3
// 186.037 us; speedup vs baseline: 1.0506x; 1.0397x over previous
//
#include <hip/hip_runtime.h>
#include <cstdint>

typedef unsigned short ushort_t;
typedef short short8 __attribute__((ext_vector_type(8)));
typedef float f32x4 __attribute__((ext_vector_type(4)));
typedef float float4v __attribute__((ext_vector_type(4)));
typedef unsigned int uint2v __attribute__((ext_vector_type(2)));

#define DDIM 1024
#define HH 16
#define HEADK 64
#define BB 2
#define SS 2048

#if __has_builtin(__builtin_amdgcn_exp2f)
#define EXP2F(x) __builtin_amdgcn_exp2f(x)
#else
#define EXP2F(x) exp2f(x)
#endif

__device__ __forceinline__ ushort_t f2bf(float f) {
  union { float f; uint32_t u; } c; c.f = f;
  uint32_t u = c.u;
  u += 0x7fffu + ((u >> 16) & 1u);
  return (ushort_t)(u >> 16);
}

// truncation-pack two fp32 -> bf16x2 (1 v_perm). Bias cancels in l-normalization.
__device__ __forceinline__ uint32_t pkbf_trunc(float a, float b) {
  union { float f; uint32_t u; } ca, cb;
  ca.f = a; cb.f = b;
  return __builtin_amdgcn_perm(cb.u, ca.u, 0x07060302);
}

__device__ __forceinline__ uint32_t pkbf_rne(float a, float b) {
  return (uint32_t)f2bf(a) | ((uint32_t)f2bf(b) << 16);
}

__device__ __forceinline__ float bfhi2f(uint32_t u) {  // high half
  union { uint32_t u; float f; } c; c.u = u & 0xffff0000u; return c.f;
}
__device__ __forceinline__ float bflo2f(uint32_t u) {  // low half
  union { uint32_t u; float f; } c; c.u = u << 16; return c.f;
}

__device__ __forceinline__ void glds16(const ushort_t* gp, ushort_t* lp) {
  __builtin_amdgcn_global_load_lds(
      (const __attribute__((address_space(1))) uint32_t*)gp,
      (__attribute__((address_space(3))) uint32_t*)lp, 16, 0, 0);
}

// ---------------- fp32 -> bf16 convert, 3 tensors in one launch ----------------
__global__ void cvt3_kernel(const float* __restrict__ s0, ushort_t* __restrict__ d0, int n0,
                            const float* __restrict__ s1, ushort_t* __restrict__ d1, int n1,
                            const float* __restrict__ s2, ushort_t* __restrict__ d2, int n2) {
  int i = blockIdx.x * blockDim.x + threadIdx.x;
  const float* src; ushort_t* dst; int k;
  if (i < n0) { src = s0; dst = d0; k = i; }
  else if (i < n0 + n1) { src = s1; dst = d1; k = i - n0; }
  else if (i < n0 + n1 + n2) { src = s2; dst = d2; k = i - n0 - n1; }
  else return;
  float4v v = ((const float4v*)src)[k];
  uint2v o; o[0] = pkbf_rne(v[0], v[1]); o[1] = pkbf_rne(v[2], v[3]);
  ((uint2v*)dst)[k] = o;
}

// ---------------- 256x256 8-wave QKV GEMM (replaces gemm_nt MODE 0) ----------------
// A [4096][1024] bf16, Bm [3072][1024] bf16 (NT). Scattered bf16 output:
//   cols 0-1023   (t=0): Q * 0.125*log2e -> qkv[0][b][h][s][k]
//   cols 1024-2047(t=1): K               -> qkv[1][b][h][s][k]
//   cols 2048-3071(t=2): V TRANSPOSED    -> qkv[2][b][h][k][s]
// T3/T4: burst-prefetch K-tile t+1 at top of tile t (8 glds16/thread, FIFO),
// then s_waitcnt vmcnt(8): tile t's 8 (oldest) landed, t+1's 8 stay in flight
// across the barrier. No vmcnt(0) drain in the main loop.
// LDS 128 KB (2 x (A 32K + B 32K)) -> 1 block/CU; grid 192 = single full wave.
__global__ __launch_bounds__(512, 2) void gemm_qkv(
    const ushort_t* __restrict__ A, const ushort_t* __restrict__ Bm,
    const float* __restrict__ bias, ushort_t* __restrict__ Cbf) {
  constexpr int Kd = 1024;
  __shared__ ushort_t smem[65536];  // 128 KB
  const int tid = threadIdx.x;
  const int wv = tid >> 6, lane = tid & 63;
  const int l15 = lane & 15, quad = lane >> 4;
  const int wm = wv >> 2, wn = wv & 3;           // 2 (M) x 4 (N) wave grid
  const int tm0 = blockIdx.y * 256, tn0 = blockIdx.x * 256;
  const int lrow = lane >> 3;
  const int gcb = (lane & 7) ^ lrow;             // pre-swizzled global col-block

  f32x4 acc[8][4];
#pragma unroll
  for (int i = 0; i < 8; ++i)
#pragma unroll
    for (int j = 0; j < 4; ++j) acc[i][j] = (f32x4){0.f, 0.f, 0.f, 0.f};

  auto stage = [&](int t, int buf) {
    ushort_t* As = smem + buf * 32768;
    ushort_t* Bs = As + 16384;
    const int k0 = t * 64;
#pragma unroll
    for (int c = 0; c < 4; ++c) {
      int seg = wv * 4 + c;  // 32 segs x 8 rows = 256 rows
      glds16(A + (size_t)(tm0 + seg * 8 + lrow) * Kd + k0 + gcb * 8,
             As + seg * 512);
      glds16(Bm + (size_t)(tn0 + seg * 8 + lrow) * Kd + k0 + gcb * 8,
             Bs + seg * 512);
    }
  };

  stage(0, 0);
  for (int t = 0; t < 16; ++t) {
    const int cur = t & 1;
    asm volatile("" ::: "memory");
    __builtin_amdgcn_s_barrier();  // B1: all waves done reading buf[cur^1] (tile t-1)
    if (t + 1 < 16) {
      stage(t + 1, cur ^ 1);
      asm volatile("s_waitcnt vmcnt(8)" ::: "memory");  // tile t (oldest 8) landed
    } else {
      asm volatile("s_waitcnt vmcnt(0)" ::: "memory");
    }
    __builtin_amdgcn_s_barrier();  // B2: tile t landed for every wave
    asm volatile("" ::: "memory");
    __builtin_amdgcn_sched_barrier(0);

    const ushort_t* As = smem + cur * 32768;
    const ushort_t* Bs = As + 16384;
    short8 bfr[4][2];
#pragma unroll
    for (int j = 0; j < 4; ++j)
#pragma unroll
      for (int kc = 0; kc < 2; ++kc) {
        int n = wn * 64 + j * 16 + l15;
        bfr[j][kc] =
            *(const short8*)(Bs + n * 64 + (((kc * 4 + quad) ^ (l15 & 7)) << 3));
      }
#pragma unroll
    for (int q = 0; q < 4; ++q) {
      short8 af[2][2];
#pragma unroll
      for (int i2 = 0; i2 < 2; ++i2)
#pragma unroll
        for (int kc = 0; kc < 2; ++kc) {
          int r = wm * 128 + (q * 2 + i2) * 16 + l15;
          af[i2][kc] =
              *(const short8*)(As + r * 64 + (((kc * 4 + quad) ^ (l15 & 7)) << 3));
        }
      __builtin_amdgcn_s_setprio(1);
#pragma unroll
      for (int kc = 0; kc < 2; ++kc)
#pragma unroll
        for (int i2 = 0; i2 < 2; ++i2)
#pragma unroll
          for (int j = 0; j < 4; ++j)
            acc[q * 2 + i2][j] = __builtin_amdgcn_mfma_f32_16x16x32_bf16(
                af[i2][kc], bfr[j][kc], acc[q * 2 + i2][j], 0, 0, 0);
      __builtin_amdgcn_s_setprio(0);
    }
  }

  const int tsel = tn0 >> 10;  // constant per block (256 | 1024)
  if (tsel < 2) {
#pragma unroll
    for (int j = 0; j < 4; ++j) {
      int col = tn0 + wn * 64 + j * 16 + l15;
      float bv = bias[col];
      int hh = (col >> 6) & 15, kk2 = col & 63;
#pragma unroll
      for (int mi = 0; mi < 8; ++mi) {
        int row0 = tm0 + wm * 128 + mi * 16 + quad * 4;
#pragma unroll
        for (int r = 0; r < 4; ++r) {
          int row = row0 + r;
          int b = row >> 11, s = row & 2047;
          float v = acc[mi][j][r] + bv;
          if (tsel == 0) v *= 0.18033688f;  // 0.125*log2(e)
          size_t base = (((size_t)tsel * BB + b) * HH + hh) * ((size_t)SS * HEADK);
          Cbf[base + (size_t)s * HEADK + kk2] = f2bf(v);
        }
      }
    }
  } else {
    // V: transpose via per-wave 16 KB LDS slab (64 cols x 128 rows)
    __builtin_amdgcn_s_barrier();  // main-loop LDS reads all complete
    ushort_t* slab = smem + wv * 8192;
#pragma unroll
    for (int j = 0; j < 4; ++j) {
      int c = j * 16 + l15;
      float bv = bias[tn0 + wn * 64 + c];
#pragma unroll
      for (int mi = 0; mi < 8; ++mi) {
        int row0 = mi * 16 + quad * 4;
        uint2v dw;
        dw[0] = pkbf_rne(acc[mi][j][0] + bv, acc[mi][j][1] + bv);
        dw[1] = pkbf_rne(acc[mi][j][2] + bv, acc[mi][j][3] + bv);
        int rb = row0 >> 3;
        *(uint2v*)(&slab[c * 128 + (((rb ^ (c & 15)) << 3) | (row0 & 7))]) = dw;
      }
    }
    // same-wave DS ops are ordered: reads below see the writes above
    const int r2 = lane & 15, cg = lane >> 4;
#pragma unroll
    for (int it = 0; it < 16; ++it) {
      int c = it * 4 + cg;  // 0..63
      short8 vv = *(const short8*)(&slab[c * 128 + ((r2 ^ (c & 15)) << 3)]);
      int gcol = tn0 + wn * 64 + c;
      int hh = (gcol >> 6) & 15, kk2 = gcol & 63;
      int grow = tm0 + wm * 128 + r2 * 8;
      int b = grow >> 11, s = grow & 2047;
      size_t base = (((size_t)2 * BB + b) * HH + hh) * ((size_t)SS * HEADK);
      *(short8*)(&Cbf[base + (size_t)kk2 * SS + s]) = vv;
    }
  }
}

// ---------------- NT GEMM (output projection): C[M,N] = A*Bm^T + bias ----------------
template <int MODE, int TM>
__global__ __launch_bounds__(256) void gemm_nt(
    const ushort_t* __restrict__ A, const ushort_t* __restrict__ Bm,
    const float* __restrict__ bias, float* __restrict__ Cout,
    ushort_t* __restrict__ Cbf, int M, int N, int Kd) {
  __shared__ ushort_t smem[128 * 64 * 2];
  ushort_t* As = smem;
  ushort_t* Bs = smem + TM * 64;
  const int MI = TM / 32;
  const int tid = threadIdx.x;
  const int wv = tid >> 6, lane = tid & 63;
  const int l15 = lane & 15, quad = lane >> 4;
  const int wm = wv >> 1, wn = wv & 1;
  const int tm0 = blockIdx.y * TM, tn0 = blockIdx.x * 128;

  f32x4 acc[MI][4];
#pragma unroll
  for (int i = 0; i < MI; ++i)
#pragma unroll
    for (int j = 0; j < 4; ++j) acc[i][j] = (f32x4){0.f, 0.f, 0.f, 0.f};

  const int lrow = lane >> 3;
  const int gcb = (lane & 7) ^ lrow;
  const int ACI = TM / 32;

  for (int k0 = 0; k0 < Kd; k0 += 64) {
#pragma unroll
    for (int c = 0; c < ACI; ++c) {
      int seg = wv * ACI + c;
      glds16(A + (size_t)(tm0 + seg * 8 + lrow) * Kd + k0 + gcb * 8,
             As + seg * 512);
    }
#pragma unroll
    for (int c = 0; c < 4; ++c) {
      int seg = wv * 4 + c;
      glds16(Bm + (size_t)(tn0 + seg * 8 + lrow) * Kd + k0 + gcb * 8,
             Bs + seg * 512);
    }
    __syncthreads();
#pragma unroll
    for (int kk = 0; kk < 64; kk += 32) {
      short8 af[MI], bfr[4];
#pragma unroll
      for (int i = 0; i < MI; ++i) {
        int r = wm * (TM / 2) + i * 16 + l15;
        int cb = (kk >> 3) + quad;
        af[i] = *(const short8*)(As + r * 64 + ((cb ^ (l15 & 7)) << 3));
      }
#pragma unroll
      for (int j = 0; j < 4; ++j) {
        int r = wn * 64 + j * 16 + l15;
        int cb = (kk >> 3) + quad;
        bfr[j] = *(const short8*)(Bs + r * 64 + ((cb ^ (l15 & 7)) << 3));
      }
#pragma unroll
      for (int i = 0; i < MI; ++i)
#pragma unroll
        for (int j = 0; j < 4; ++j)
          acc[i][j] = __builtin_amdgcn_mfma_f32_16x16x32_bf16(
              af[i], bfr[j], acc[i][j], 0, 0, 0);
    }
    __syncthreads();
  }

  if (MODE == 1) {
#pragma unroll
    for (int j = 0; j < 4; ++j) {
      int col = tn0 + wn * 64 + j * 16 + l15;
      float bv = bias[col];
#pragma unroll
      for (int i = 0; i < MI; ++i) {
        int row0 = tm0 + wm * (TM / 2) + i * 16 + quad * 4;
#pragma unroll
        for (int r = 0; r < 4; ++r)
          Cout[(size_t)(row0 + r) * N + col] = acc[i][j][r] + bv;
      }
    }
  }
}

// ---------------- flash attention, KV-split, software-pipelined ----------------
// grid (16,16,BB*NSPLIT): qt=bx (128 q-rows), h=by, z: b=z/NSPLIT, ns=z%NSPLIT.
// 4 waves x 32 q-rows; KV tile 32, triple-buffered K/V, staged 2 tiles ahead.
// T15-style pipeline: iteration j computes QK^T(j+1) -> exp2 -> P write into
// ping-pong Pw[(j+1)&1], then PV(j) consuming P written ONE ITERATION AGO.
// Max-free exp2 softmax => partials exactly additive: block writes
// unnormalized O^T (bf16, per-split buffer) + l (fp32); reduce combines.
template <int NSPLIT>
__global__ __launch_bounds__(256, 4) void attn_kernel(
    const ushort_t* __restrict__ qkv, ushort_t* __restrict__ O0,
    ushort_t* __restrict__ O1, float* __restrict__ Lp) {
  constexpr int NT = (SS / NSPLIT) / 32;  // KV tiles per block
  __shared__ ushort_t Kt[3][32 * 64];     // [pos32][feat64], XOR-swizzled
  __shared__ ushort_t Vt[3][64 * 32];     // [feat64][pos32], XOR-swizzled
  __shared__ ushort_t Pw[4][2][32 * 32];  // per-wave P, ping-pong; epilogue slab

  const int qt = blockIdx.x, h = blockIdx.y;
  const int b = blockIdx.z / NSPLIT, ns = blockIdx.z % NSPLIT;
  const int tid = threadIdx.x;
  const int wv = tid >> 6, lane = tid & 63;
  const int l15 = lane & 15, quad = lane >> 4;

  const size_t hstride = (size_t)SS * HEADK;
  const ushort_t* Qg = qkv + ((size_t)(0 * BB + b) * HH + h) * hstride;
  const ushort_t* Kg = qkv + ((size_t)(1 * BB + b) * HH + h) * hstride;
  const ushort_t* Vg = qkv + ((size_t)(2 * BB + b) * HH + h) * hstride; // [64][2048]
  ushort_t* Opp = ns ? O1 : O0;

  short8 qf[2][2];
#pragma unroll
  for (int mi = 0; mi < 2; ++mi)
#pragma unroll
    for (int kc = 0; kc < 2; ++kc)
      qf[mi][kc] = *(const short8*)(
          Qg + (size_t)(qt * 128 + wv * 32 + mi * 16 + l15) * 64 + kc * 32 +
          quad * 8);

  const short ONE = (short)0x3F80;
  short8 ones = {ONE, ONE, ONE, ONE, ONE, ONE, ONE, ONE};

  f32x4 oat[2][4];  // O^T rows feat=cf*16+quad*4+r, col qrow=l15
  f32x4 loa[2];
#pragma unroll
  for (int mi = 0; mi < 2; ++mi) {
    loa[mi] = (f32x4){0.f, 0.f, 0.f, 0.f};
#pragma unroll
    for (int c = 0; c < 4; ++c) oat[mi][c] = (f32x4){0.f, 0.f, 0.f, 0.f};
  }

  const int lrow = lane >> 3, gcb = (lane & 7) ^ lrow;   // K staging
  const int vfl = lane >> 2;                              // V staging feat 0..15
  const int vgb = (lane & 3) ^ ((vfl >> 1) & 3);          // V global pos-block

  const int pos0 = ns * (SS / NSPLIT);

  // 2 glds16 per wave per tile
  auto stage = [&](int jj, int db) {
    glds16(Kg + (size_t)(pos0 + jj * 32 + wv * 8 + lrow) * 64 + gcb * 8,
           &Kt[db][wv * 512]);
    glds16(Vg + (size_t)(wv * 16 + vfl) * SS + pos0 + jj * 32 + vgb * 8,
           &Vt[db][wv * 512]);
  };

  // QK^T(tile in Kt[kb]) -> exp2 -> P into Pw[wv][pb]
  auto qk_phase = [&](int kb, int pb) {
    f32x4 st[2][2];
    __builtin_amdgcn_s_setprio(1);
#pragma unroll
    for (int cf = 0; cf < 2; ++cf) {
      int n = cf * 16 + l15;
      short8 kf0 = *(const short8*)(&Kt[kb][n * 64 + ((quad ^ (n & 7)) << 3)]);
      short8 kf1 =
          *(const short8*)(&Kt[kb][n * 64 + (((quad + 4) ^ (n & 7)) << 3)]);
#pragma unroll
      for (int mi = 0; mi < 2; ++mi) {
        f32x4 z = (f32x4){0.f, 0.f, 0.f, 0.f};
        z = __builtin_amdgcn_mfma_f32_16x16x32_bf16(kf0, qf[mi][0], z, 0, 0, 0);
        z = __builtin_amdgcn_mfma_f32_16x16x32_bf16(kf1, qf[mi][1], z, 0, 0, 0);
        st[mi][cf] = z;
      }
    }
    __builtin_amdgcn_s_setprio(0);
#pragma unroll
    for (int mi = 0; mi < 2; ++mi)
#pragma unroll
      for (int cf = 0; cf < 2; ++cf) {
        float e0 = EXP2F(st[mi][cf][0]);
        float e1 = EXP2F(st[mi][cf][1]);
        float e2 = EXP2F(st[mi][cf][2]);
        float e3 = EXP2F(st[mi][cf][3]);
        uint2v dw;
        dw[0] = pkbf_trunc(e0, e1);
        dw[1] = pkbf_trunc(e2, e3);
        int row = mi * 16 + l15;
        int pbv = 2 * cf + (quad >> 1);
        int pbs = pbv ^ ((l15 >> 1) & 3);
        *(uint2v*)(&Pw[wv][pb][row * 32 + pbs * 8 + (quad & 1) * 4]) = dw;
      }
  };

  stage(0, 0);
  stage(1, 1);

  // prologue: tile 0's K landed everywhere -> QK(0), P(0) -> Pw[0]
  asm volatile("s_waitcnt vmcnt(2)" ::: "memory");
  __builtin_amdgcn_s_barrier();
  asm volatile("" ::: "memory");
  __builtin_amdgcn_sched_barrier(0);
  qk_phase(0, 0);

  int vb = 0;  // buffer holding tile j
  for (int j = 0; j < NT; ++j) {
    const int kb = (vb == 2) ? 0 : vb + 1;   // tile j+1
    const int sb = (kb == 2) ? 0 : kb + 1;   // tile j+2 (overwrites tile j-1)
    asm volatile("s_waitcnt vmcnt(0)" ::: "memory");
    __builtin_amdgcn_s_barrier();
    asm volatile("" ::: "memory");
    __builtin_amdgcn_sched_barrier(0);

    if (j + 2 < NT) stage(j + 2, sb);
    if (j + 1 < NT) qk_phase(kb, (j + 1) & 1);

    // PV(j): consume P written one iteration ago (same-wave DS ordering)
    short8 pa[2];
#pragma unroll
    for (int mi = 0; mi < 2; ++mi) {
      int row = mi * 16 + l15;
      pa[mi] = *(const short8*)(&Pw[wv][j & 1][row * 32 +
                                              ((quad ^ ((l15 >> 1) & 3)) << 3)]);
    }
    __builtin_amdgcn_s_setprio(1);
#pragma unroll
    for (int cf = 0; cf < 4; ++cf) {
      short8 vf = *(const short8*)(&Vt[vb][(cf * 16 + l15) * 32 +
                                           ((quad ^ ((l15 >> 1) & 3)) << 3)]);
#pragma unroll
      for (int mi = 0; mi < 2; ++mi)
        oat[mi][cf] = __builtin_amdgcn_mfma_f32_16x16x32_bf16(
            vf, pa[mi], oat[mi][cf], 0, 0, 0);
    }
#pragma unroll
    for (int mi = 0; mi < 2; ++mi)
      loa[mi] = __builtin_amdgcn_mfma_f32_16x16x32_bf16(ones, pa[mi], loa[mi],
                                                        0, 0, 0);
    __builtin_amdgcn_s_setprio(0);

    vb = kb;
  }

  // epilogue: unnormalized O^T -> [qrow][feat] via per-wave Pw slab (16x64)
  const size_t obase = ((size_t)b * HH + h) * SS * HEADK;  // Opp[b][h][qrow][64]
#pragma unroll
  for (int mi = 0; mi < 2; ++mi) {
#pragma unroll
    for (int cf = 0; cf < 4; ++cf) {
      uint2v dw;
      dw[0] = pkbf_rne(oat[mi][cf][0], oat[mi][cf][1]);
      dw[1] = pkbf_rne(oat[mi][cf][2], oat[mi][cf][3]);
      int cb = 2 * cf + (quad >> 1);
      int cbs = cb ^ (l15 & 7);
      *(uint2v*)(&Pw[wv][0][l15 * 64 + cbs * 8 + (quad & 1) * 4]) = dw;
    }
    // same-wave DS ops are ordered: reads below see the writes above
    const int r = lane >> 2;
#pragma unroll
    for (int pass = 0; pass < 2; ++pass) {
      int g = (lane & 3) + 4 * pass;
      short8 ov = *(const short8*)(&Pw[wv][0][r * 64 + ((g ^ (r & 7)) << 3)]);
      int qrow = qt * 128 + wv * 32 + mi * 16 + r;
      *(short8*)(&Opp[obase + (size_t)qrow * 64 + g * 8]) = ov;
    }
    if (quad == 0) {
      int qrow = qt * 128 + wv * 32 + mi * 16 + l15;
      Lp[((size_t)(ns * BB + b) * HH + h) * SS + qrow] = loa[mi][0];
    }
  }
}

// ---------------- combine the NSPLIT KV-split partials ----------------
template <int NSPLIT>
__global__ void reduce_kernel(const ushort_t* __restrict__ O0,
                              const ushort_t* __restrict__ O1,
                              const float* __restrict__ Lp,
                              ushort_t* __restrict__ ob) {
  const size_t nsL = (size_t)BB * HH * SS;
  int c = blockIdx.x * blockDim.x + threadIdx.x;     // 8-elem chunk id
  int fc = c & 7;
  int hh = (c >> 3) & 15;
  int row = c >> 7;                                  // b*2048 + s
  int b = row >> 11, s = row & 2047;
  size_t po = (((size_t)b * HH + hh) * SS + s) * 64 + fc * 8;
  size_t lo = ((size_t)b * HH + hh) * SS + s;
  const ushort_t* Ops[2] = {O0, O1};
  float acc[8];
#pragma unroll
  for (int i = 0; i < 8; ++i) acc[i] = 0.f;
  float l = 0.f;
#pragma unroll
  for (int t = 0; t < NSPLIT; ++t) {
    uint2v a0 = *(const uint2v*)(&Ops[t][po]);
    uint2v a1 = *(const uint2v*)(&Ops[t][po + 4]);
    acc[0] += bflo2f(a0[0]); acc[1] += bfhi2f(a0[0]);
    acc[2] += bflo2f(a0[1]); acc[3] += bfhi2f(a0[1]);
    acc[4] += bflo2f(a1[0]); acc[5] += bfhi2f(a1[0]);
    acc[6] += bflo2f(a1[1]); acc[7] += bfhi2f(a1[1]);
    l += Lp[(size_t)t * nsL + lo];
  }
  float inv = 1.0f / l;
  uint2v o0, o1;
  o0[0] = pkbf_rne(acc[0] * inv, acc[1] * inv);
  o0[1] = pkbf_rne(acc[2] * inv, acc[3] * inv);
  o1[0] = pkbf_rne(acc[4] * inv, acc[5] * inv);
  o1[1] = pkbf_rne(acc[6] * inv, acc[7] * inv);
  size_t oo = ((size_t)(b * SS + s)) * DDIM + hh * 64 + fc * 8;
  *(uint2v*)(&ob[oo]) = o0;
  *(uint2v*)(&ob[oo + 4]) = o1;
}

extern "C" void kernel_launch(void* const* d_in, const int* in_sizes, int n_in,
                              void* d_out, int out_size, void* d_ws,
                              size_t ws_size, hipStream_t stream) {
  const float* x = (const float*)d_in[0];
  const float* Wqkv = (const float*)d_in[1];
  const float* bqkv = (const float*)d_in[2];
  const float* Wproj = (const float*)d_in[3];
  const float* bproj = (const float*)d_in[4];
  float* out = (float*)d_out;

  // Workspace plan (peak 50.33 MB, identical to proven rounds 1-11):
  //   [0      .. 4.19M)  xb   (GEMM1 A)      -> reused as Op0 by attn
  //   [4.19M  .. 7.34M)  wqb  (GEMM1 B)      -> reused as Lp by attn
  //   [7.34M  .. 8.39M)  wpb  (GEMM2 B, alive throughout)
  //   [8.39M  .. 20.97M) qkvb (attn input)   -> reused as obuf by reduce
  //   [20.97M .. 25.17M) Op1
  ushort_t* xb = (ushort_t*)d_ws;
  ushort_t* wqb = xb + (size_t)4096 * 1024;
  ushort_t* wpb = wqb + (size_t)3072 * 1024;
  ushort_t* qkvb = wpb + (size_t)1024 * 1024;
  ushort_t* Op1 = qkvb + (size_t)3 * BB * HH * SS * HEADK;
  ushort_t* Op0 = xb;
  float* Lp = (float*)wqb;
  ushort_t* obuf = qkvb;

  const int n0 = 4096 * 1024 / 4, n1 = 3072 * 1024 / 4, n2 = 1024 * 1024 / 4;
  cvt3_kernel<<<(n0 + n1 + n2 + 255) / 256, 256, 0, stream>>>(
      x, xb, n0, Wqkv, wqb, n1, Wproj, wpb, n2);
  gemm_qkv<<<dim3(3072 / 256, 4096 / 256), 512, 0, stream>>>(xb, wqb, bqkv,
                                                             qkvb);
  attn_kernel<2><<<dim3(16, 16, BB * 2), 256, 0, stream>>>(qkvb, Op0, Op1, Lp);
  reduce_kernel<2><<<(BB * SS * DDIM / 8) / 256, 256, 0, stream>>>(Op0, Op1,
                                                                   Lp, obuf);
  gemm_nt<1, 64><<<dim3(1024 / 128, 4096 / 64), 256, 0, stream>>>(
      obuf, wpb, bproj, out, nullptr, 4096, 1024, 1024);
}